// Round 3
// baseline (279.208 us; speedup 1.0000x reference)
//
#include <hip/hip_runtime.h>
#include <stdint.h>

#define T_DIM 2048
#define V_DIM 1024
#define B_DIM 8

typedef unsigned int u32;
typedef unsigned short u16;
typedef __attribute__((ext_vector_type(8))) short s16x8;
typedef __attribute__((ext_vector_type(4))) float f32x4;

__device__ __forceinline__ u16 f2bf(float x) {
  u32 u = __builtin_bit_cast(u32, x);
  u = u + 0x7FFFu + ((u >> 16) & 1u);   // round-to-nearest-even
  return (u16)(u >> 16);
}

// async global->LDS, 16B per lane (m97 pattern)
#define GLD16(gp, lp) __builtin_amdgcn_global_load_lds( \
    (const __attribute__((address_space(1))) u32*)(gp), \
    (__attribute__((address_space(3))) u32*)(lp), 16, 0, 0)

// ---------------------------------------------------------------------------
// Legacy 128x128 kernel — kept for the small V x V GEMM (M = Wq^T Wk) only.
// ---------------------------------------------------------------------------
template<int MODE, bool F32OUT>
__global__ void __launch_bounds__(256, 2)
gemm_bt(const u16* __restrict__ A, int lda, long long batchA,
        const u16* __restrict__ Bt, int ldb, long long batchB,
        void* __restrict__ Cv, int ldc, long long batchC,
        int K, float bias)
{
  int bn = blockIdx.x, bm = blockIdx.y, bz = blockIdx.z;
  const u16* Ab = A + (long long)bz * batchA;
  const u16* Bb = Bt + (long long)bz * batchB;
  int m0 = bm * 128, n0 = bn * 128;
  int kmax = K;

  __shared__ u16 As[128 * 64];
  __shared__ u16 Bs[128 * 64];

  int tid = threadIdx.x;
  int lane = tid & 63;
  int wid = tid >> 6;
  int wm = wid >> 1, wn = wid & 1;

  f32x4 acc[4][4] = {};

  int r0 = tid >> 3;
  int gcol = (((tid & 7) - r0) & 7) * 8;
  const u16* ga = Ab + (long long)(m0 + r0) * lda + gcol;
  const u16* gb = Bb + (long long)(n0 + r0) * ldb + gcol;
  u16* la = As + tid * 8;
  u16* lb = Bs + tid * 8;
  long long lda32 = (long long)32 * lda;
  long long ldb32 = (long long)32 * ldb;

  int rm = lane & 15;
  int q = lane >> 4;

  for (int k0 = 0; k0 < kmax; k0 += 64) {
#pragma unroll
    for (int i = 0; i < 4; i++)
      GLD16(ga + k0 + i * lda32, la + i * 2048);
#pragma unroll
    for (int i = 0; i < 4; i++)
      GLD16(gb + k0 + i * ldb32, lb + i * 2048);
    __syncthreads();
#pragma unroll
    for (int ks = 0; ks < 2; ks++) {
      s16x8 af[4], bfv[4];
#pragma unroll
      for (int mi = 0; mi < 4; mi++) {
        int row = wm * 64 + mi * 16 + rm;
        int p = ((ks * 4 + q) + row) & 7;
        af[mi] = *(const s16x8*)&As[row * 64 + p * 8];
      }
#pragma unroll
      for (int ni = 0; ni < 4; ni++) {
        int row = wn * 64 + ni * 16 + rm;
        int p = ((ks * 4 + q) + row) & 7;
        bfv[ni] = *(const s16x8*)&Bs[row * 64 + p * 8];
      }
#pragma unroll
      for (int mi = 0; mi < 4; mi++)
#pragma unroll
        for (int ni = 0; ni < 4; ni++)
          acc[mi][ni] = __builtin_amdgcn_mfma_f32_16x16x32_bf16(
              af[mi], bfv[ni], acc[mi][ni], 0, 0, 0);
    }
    __syncthreads();
  }

  int col = lane & 15;
  int rq = (lane >> 4) * 4;
#pragma unroll
  for (int mi = 0; mi < 4; mi++) {
#pragma unroll
    for (int ni = 0; ni < 4; ni++) {
      int lr = wm * 64 + mi * 16 + rq;
      int lc = wn * 64 + ni * 16 + col;
#pragma unroll
      for (int rr = 0; rr < 4; rr++) {
        float val = acc[mi][ni][rr];
        long long off = (long long)(m0 + lr + rr) * ldc + (n0 + lc);
        if (F32OUT) {
          float* C = (float*)Cv + (long long)bz * batchC;
          C[off] = val + bias;
        } else {
          u16* C = (u16*)Cv + (long long)bz * batchC;
          C[off] = f2bf(val);
        }
      }
    }
  }
}

// ---------------------------------------------------------------------------
// gemm8: faithful m201 8-phase port. 256x256 tile, BK=64, 8 waves (2M x 4N),
// per-wave output 128x64 (8mi x 4ni 16x16x32 frags), fp32 accum.
// LDS 2 x 64KB K-tile buffers (X=even tiles buf0, Y=odd buf1), each:
//   A-half h at h*8192, B-half h at 16384+h*8192 (elems), rows r'=0..127 x 64k,
//   rotation swizzle: slot p of row r' holds chunk (p-r')&7 (0 bank conflicts).
// Iteration = 2 K-tiles = 8 phases; each phase:
//   {4-8 ds_read_b128 (pre-barrier!) ; 0-3 half-tile stages (2xGLD16 each);
//    [vmcnt at P4/P8] ; s_barrier ; lgkmcnt(0)+sched_barrier ;
//    setprio(1) ; 16 independent MFMA ; setprio(0) ; s_barrier}
// Phase->work: P1 X(q0,ks0)+B(ks0); P2 X(q1,ks0); P3 X(q0,ks1)+B(ks1);
//   P4 X(q1,ks1); P5-P8 same on Y.  B-frags live 2 phases (reg reuse).
// Stage schedule (tile pk=2j+2 -> buf0, pk+1 -> buf1), each target region
// sealed by the barrier after its last read:  P1: Y.A1(cur Y tile!);
//   P4: X.A0+X.B0 +vmcnt(4); P5: X.B1+X.A1; P8: Y.A0+Y.B0+Y.B1 +vmcnt(6).
// Every drained load has >=3 phases of lead (the guide's 3-half-tiles /
// N=2x3=6 steady state). vmcnt(0) only when nothing is prefetched (last iter).
// MODE 1: A = tril(G*P^T), tiles n<=m, nk=(n+1)*4, bf16 out + tril mask,
//   LPT n-desc.  MODE 2: out = A*Yt^T + bias, nk=(m+1)*4, f32 out, LPT m-desc.
// K-truncation multiplies exact zeros => bit-identical.
// ---------------------------------------------------------------------------
#define BUFE 32768

#define STAGE_A(h, bb, kt) { \
  GLD16(gA[h][0] + (kt) * 64, &lds[(bb) + lA[h][0]]); \
  GLD16(gA[h][1] + (kt) * 64, &lds[(bb) + lA[h][1]]); }
#define STAGE_B(h, bb, kt) { \
  GLD16(gB[h][0] + (kt) * 64, &lds[(bb) + lB[h][0]]); \
  GLD16(gB[h][1] + (kt) * 64, &lds[(bb) + lB[h][1]]); }

#define DS_A(quad, ksv, bb) { \
  _Pragma("unroll") \
  for (int mi = 0; mi < 4; mi++) \
    af[mi] = *(const s16x8*)&lds[(bb) + abase[ksv] + ((quad) * 4 + mi) * 1024]; }
#define DS_B(ksv, bb) { \
  _Pragma("unroll") \
  for (int ni = 0; ni < 4; ni++) \
    bf[ni] = *(const s16x8*)&lds[(bb) + bbase[ksv] + ni * 1024]; }

#define MFMA16(quad) { \
  __builtin_amdgcn_s_setprio(1); \
  _Pragma("unroll") \
  for (int mi = 0; mi < 4; mi++) \
    _Pragma("unroll") \
    for (int ni = 0; ni < 4; ni++) \
      acc[(quad) * 4 + mi][ni] = __builtin_amdgcn_mfma_f32_16x16x32_bf16( \
          af[mi], bf[ni], acc[(quad) * 4 + mi][ni], 0, 0, 0); \
  __builtin_amdgcn_s_setprio(0); }

#define BARS() { __builtin_amdgcn_s_barrier(); __builtin_amdgcn_sched_barrier(0); }
#define LGKM0() { asm volatile("s_waitcnt lgkmcnt(0)" ::: "memory"); \
                  __builtin_amdgcn_sched_barrier(0); }
#define VMC(n) asm volatile("s_waitcnt vmcnt(" #n ")" ::: "memory")

template<int MODE>
__global__ void __launch_bounds__(512, 2)
gemm8(const u16* __restrict__ Ag, int lda, long long batchA,
      const u16* __restrict__ Btg, int ldb, long long batchB,
      void* __restrict__ Cv, int ldc, long long batchC,
      float bias, int lnb)
{
  int lam = blockIdx.x;
  int bz = lam & ((1 << lnb) - 1);
  int tau = lam >> lnb;
  int m, n;
  if (MODE == 1) {
    int nn = 7, off = 0;                 // n descending = heavy first (LPT)
    while (tau >= off + (8 - nn)) { off += 8 - nn; nn--; }
    n = nn; m = nn + (tau - off);
  } else {
    m = 7 - (tau >> 2);                  // m descending = heavy first (LPT)
    n = tau & 3;
  }
  const int m0 = m * 256, n0 = n * 256;
  const int nk = ((MODE == 1 ? n : m) + 1) * 4;   // 64-K tiles; multiple of 4

  const u16* __restrict__ Ab = Ag + (long long)bz * batchA;
  const u16* __restrict__ Bb = Btg + (long long)bz * batchB;

  __shared__ u16 lds[2 * BUFE];          // 128 KiB

  const int tid = threadIdx.x;
  const int lane = tid & 63;
  const int wid = tid >> 6;
  const int wm = wid >> 2, wn = wid & 3;

  // ---- staging descriptors: [half][line]; line l covers f = l*512+tid ----
  const u16 *gA[2][2], *gB[2][2];
  int lA[2][2], lB[2][2];
#pragma unroll
  for (int h = 0; h < 2; h++)
#pragma unroll
    for (int l = 0; l < 2; l++) {
      int f = l * 512 + tid, r = f >> 3, c = ((f & 7) - r) & 7;
      gA[h][l] = Ab + (long long)(m0 + h * 128 + r) * lda + c * 8;
      gB[h][l] = Bb + (long long)(n0 + h * 128 + r) * ldb + c * 8;
      lA[h][l] = h * 8192 + f * 8;
      lB[h][l] = 16384 + h * 8192 + f * 8;
    }

  // ---- fragment LDS base offsets; frag addr = base[ks] + (quad*4+mi)*1024 ----
  const int rm = lane & 15, q = lane >> 4;
  int abase[2], bbase[2];
#pragma unroll
  for (int ks = 0; ks < 2; ks++) {
    abase[ks] = wm * 8192 + rm * 64 + (((ks * 4 + q) + rm) & 7) * 8;
    bbase[ks] = 16384 + (wn >> 1) * 8192 + ((wn & 1) * 64 + rm) * 64
              + (((ks * 4 + q) + rm) & 7) * 8;
  }

  f32x4 acc[8][4] = {};

  // ---- prologue: X(tile0) all 4 halves; Y(tile1) A0,B0,B1 (A1 at P1) ----
  STAGE_A(0, 0, 0); STAGE_B(0, 0, 0); STAGE_B(1, 0, 0); STAGE_A(1, 0, 0);
  STAGE_A(0, BUFE, 1); STAGE_B(0, BUFE, 1); STAGE_B(1, BUFE, 1);
  VMC(6);                                // drain X's 8, leave Y's 6 in flight
  __builtin_amdgcn_s_barrier();
  __builtin_amdgcn_sched_barrier(0);

  const int niter = nk >> 1;
  for (int j = 0; j < niter; ++j) {
    const int ktY = 2 * j + 1;
    const int pk = 2 * j + 2;
    const bool pf = pk < nk;
    s16x8 af[4], bf[4];

    // P1: X q0 ks0 + B ks0; stage Y.A1 (current Y tile)
    DS_A(0, 0, 0); DS_B(0, 0);
    STAGE_A(1, BUFE, ktY);
    BARS(); LGKM0(); MFMA16(0); BARS();
    // P2: X q1 ks0 (bf reg reuse)
    DS_A(1, 0, 0);
    BARS(); LGKM0(); MFMA16(1); BARS();
    // P3: X q0 ks1 + B ks1
    DS_A(0, 1, 0); DS_B(1, 0);
    BARS(); LGKM0(); MFMA16(0); BARS();
    // P4: X q1 ks1; stage X'(pk): A0,B0; vmcnt drains Y (3-phase lead)
    DS_A(1, 1, 0);
    if (pf) { STAGE_A(0, 0, pk); STAGE_B(0, 0, pk); VMC(4); }
    else    { VMC(0); }
    BARS(); LGKM0(); MFMA16(1); BARS();
    // P5: Y q0 ks0 + B ks0; stage X'(pk): B1,A1
    DS_A(0, 0, BUFE); DS_B(0, BUFE);
    if (pf) { STAGE_B(1, 0, pk); STAGE_A(1, 0, pk); }
    BARS(); LGKM0(); MFMA16(0); BARS();
    // P6: Y q1 ks0
    DS_A(1, 0, BUFE);
    BARS(); LGKM0(); MFMA16(1); BARS();
    // P7: Y q0 ks1 + B ks1
    DS_A(0, 1, BUFE); DS_B(1, BUFE);
    BARS(); LGKM0(); MFMA16(0); BARS();
    // P8: Y q1 ks1; stage Y'(pk+1): A0,B0,B1; vmcnt drains X' (3-phase lead)
    DS_A(1, 1, BUFE);
    if (pf) { STAGE_A(0, BUFE, pk + 1); STAGE_B(0, BUFE, pk + 1);
              STAGE_B(1, BUFE, pk + 1); VMC(6); }
    else    { VMC(0); }
    BARS(); LGKM0(); MFMA16(1); BARS();
  }

  // ---- epilogue: per-wave 128x64 ----
  const int col = lane & 15, rq = (lane >> 4) * 4;
  if (MODE == 2) {
    float* C = (float*)Cv + (long long)bz * batchC;
#pragma unroll
    for (int mi = 0; mi < 8; mi++) {
      int lr = m0 + wm * 128 + mi * 16 + rq;
#pragma unroll
      for (int ni = 0; ni < 4; ni++) {
        int lc = n0 + wn * 64 + ni * 16 + col;
#pragma unroll
        for (int rr = 0; rr < 4; rr++)
          C[(long long)(lr + rr) * ldc + lc] = acc[mi][ni][rr] + bias;
      }
    }
  } else {
    u16* C = (u16*)Cv + (long long)bz * batchC;
#pragma unroll
    for (int mi = 0; mi < 8; mi++) {
      int lr = m0 + wm * 128 + mi * 16 + rq;
#pragma unroll
      for (int ni = 0; ni < 4; ni++) {
        int lc = n0 + wn * 64 + ni * 16 + col;
#pragma unroll
        for (int rr = 0; rr < 4; rr++) {
          float val = acc[mi][ni][rr];
          if (lc > lr + rr) val = 0.f;           // causal mask
          C[(long long)(lr + rr) * ldc + lc] = f2bf(val);
        }
      }
    }
  }
}

// ---------------------------------------------------------------------------
// prep: z<2: transpose+cast VxV fp32 -> bf16 (dst[i][o]=src[o][i]);
//       z==2: straight cast of Wv
// ---------------------------------------------------------------------------
__global__ void prep_weights(const float* __restrict__ Wq, u16* __restrict__ WqT,
                             const float* __restrict__ Wk, u16* __restrict__ WkT,
                             const float* __restrict__ Wv, u16* __restrict__ Wvb)
{
  int z = blockIdx.z;
  if (z == 2) {
    int bx = blockIdx.y * 32 + blockIdx.x;
    int i = bx * 1024 + threadIdx.y * 32 + threadIdx.x;
#pragma unroll
    for (int k = 0; k < 4; k++) Wvb[i + k * 256] = f2bf(Wv[i + k * 256]);
    return;
  }
  const float* src = z ? Wk : Wq;
  u16* dst = z ? WkT : WqT;
  __shared__ float tile[32][33];
  int x0 = blockIdx.x * 32, y0 = blockIdx.y * 32;
  int tx = threadIdx.x, ty = threadIdx.y;
#pragma unroll
  for (int k = 0; k < 4; k++)
    tile[ty + k * 8][tx] = src[(long long)(y0 + ty + k * 8) * V_DIM + x0 + tx];
  __syncthreads();
#pragma unroll
  for (int k = 0; k < 4; k++)
    dst[(long long)(x0 + ty + k * 8) * V_DIM + y0 + tx] = f2bf(tile[tx][ty + k * 8]);
}

// P[s][u] = v[s-u] for u<=s else 0  (T x T bf16), 16B stores
__global__ void build_p(const float* __restrict__ v, u16* __restrict__ P)
{
  int gid = blockIdx.x * 256 + threadIdx.x;
  int e0 = gid * 8;
  int s = e0 >> 11, u0 = e0 & 2047;
  s16x8 o;
#pragma unroll
  for (int k = 0; k < 8; k++) {
    int u = u0 + k;
    o[k] = (short)((u <= s) ? f2bf(v[s - u]) : (u16)0);
  }
  *(s16x8*)&P[e0] = o;
}

// merged gather: bx<T: G[z][t][u]=M[idx[t]][idx[u]]; else Yt[z][j][s]=Wv[j][idx[s]]
__global__ void __launch_bounds__(256)
gather_gy(const int* __restrict__ idx, const u16* __restrict__ Mb,
          const u16* __restrict__ Wvb, u16* __restrict__ G,
          u16* __restrict__ Yt, int b0)
{
  int bx = blockIdx.x, z = blockIdx.y;
  const int* idxrow = idx + (long long)(b0 + z) * T_DIM;
  __shared__ u16 Row[V_DIM];
  int tid = threadIdx.x;
  const u32* src;
  u16* dst;
  if (bx < T_DIM) {
    src = (const u32*)(Mb + (long long)idxrow[bx] * V_DIM);
    dst = G + ((long long)z * T_DIM + bx) * T_DIM;
  } else {
    src = (const u32*)(Wvb + (long long)(bx - T_DIM) * V_DIM);
    dst = Yt + ((long long)z * V_DIM + (bx - T_DIM)) * T_DIM;
  }
  u32* dstl = (u32*)Row;
  dstl[tid] = src[tid];
  dstl[tid + 256] = src[tid + 256];
  __syncthreads();
  int s0 = tid * 8;
  int4 i0 = *(const int4*)&idxrow[s0];
  int4 i1 = *(const int4*)&idxrow[s0 + 4];
  s16x8 o;
  o[0] = (short)Row[i0.x]; o[1] = (short)Row[i0.y];
  o[2] = (short)Row[i0.z]; o[3] = (short)Row[i0.w];
  o[4] = (short)Row[i1.x]; o[5] = (short)Row[i1.y];
  o[6] = (short)Row[i1.z]; o[7] = (short)Row[i1.w];
  *(s16x8*)&dst[s0] = o;
}

// ---------------------------------------------------------------------------
extern "C" void kernel_launch(void* const* d_in, const int* in_sizes, int n_in,
                              void* d_out, int out_size, void* d_ws, size_t ws_size,
                              hipStream_t stream)
{
  const int*   idx = (const int*)d_in[0];
  const float* v   = (const float*)d_in[1];
  const float* Wk  = (const float*)d_in[2];
  const float* Wq  = (const float*)d_in[3];
  const float* Wv  = (const float*)d_in[4];
  float* out = (float*)d_out;

  char* p = (char*)d_ws;
  const size_t SZ_VV = (size_t)V_DIM * V_DIM * 2;   // 2 MB bf16
  const size_t SZ_TT = (size_t)T_DIM * T_DIM * 2;   // 8 MB bf16
  const size_t SZ_VT = (size_t)V_DIM * T_DIM * 2;   // 4 MB bf16
  u16* WqT = (u16*)p; p += SZ_VV;
  u16* WkT = (u16*)p; p += SZ_VV;
  u16* Wvb = (u16*)p; p += SZ_VV;
  u16* Mb  = (u16*)p; p += SZ_VV;
  u16* P   = (u16*)p; p += SZ_TT;
  size_t used = (size_t)(p - (char*)d_ws);
  size_t per = 2 * SZ_TT + SZ_VT;                    // G + A + Yt per batch
  int nb = 8;
  while (nb > 1 && used + (size_t)nb * per > ws_size) nb >>= 1;
  u16* G    = (u16*)p; p += (size_t)nb * SZ_TT;
  u16* Abuf = (u16*)p; p += (size_t)nb * SZ_TT;
  u16* Yt   = (u16*)p;
  int lnb = (nb == 8) ? 3 : (nb == 4) ? 2 : (nb == 2) ? 1 : 0;

  prep_weights<<<dim3(32, 32, 3), dim3(32, 8), 0, stream>>>(Wq, WqT, Wk, WkT, Wv, Wvb);
  build_p<<<2048, 256, 0, stream>>>(v, P);
  // M = Wq^T * Wk  [V,V]
  gemm_bt<0, false><<<dim3(V_DIM / 128, V_DIM / 128, 1), 256, 0, stream>>>(
      WqT, V_DIM, 0, WkT, V_DIM, 0, Mb, V_DIM, 0, V_DIM, 0.f);

  for (int b0 = 0; b0 < B_DIM; b0 += nb) {
    gather_gy<<<dim3(T_DIM + V_DIM, nb), 256, 0, stream>>>(idx, Mb, Wvb, G, Yt, b0);
    // A = tril(G * P^T): 36 tiles (256x256, n<=m) x nb, n-desc LPT
    gemm8<1><<<dim3(36 * nb), 512, 0, stream>>>(
        G, T_DIM, (long long)T_DIM * T_DIM, P, T_DIM, 0,
        Abuf, T_DIM, (long long)T_DIM * T_DIM, 0.f, lnb);
    // out = A * Yt^T + 0.001: 32 tiles (256x256) x nb, m-desc LPT
    gemm8<2><<<dim3(32 * nb), 512, 0, stream>>>(
        Abuf, T_DIM, (long long)T_DIM * T_DIM, Yt, T_DIM, (long long)V_DIM * T_DIM,
        out + (long long)b0 * T_DIM * V_DIM, V_DIM, (long long)T_DIM * V_DIM,
        0.001f, lnb);
  }
}

// Round 4
// 274.098 us; speedup vs baseline: 1.0186x; 1.0186x over previous
//
#include <hip/hip_runtime.h>
#include <stdint.h>

#define T_DIM 2048
#define V_DIM 1024
#define B_DIM 8
#define NT 16            // T_DIM/128

typedef unsigned int u32;
typedef unsigned short u16;
typedef long long ll;
typedef __attribute__((ext_vector_type(8))) short s16x8;
typedef __attribute__((ext_vector_type(4))) float f32x4;

__device__ __forceinline__ u16 f2bf(float x) {
  u32 u = __builtin_bit_cast(u32, x);
  u = u + 0x7FFFu + ((u >> 16) & 1u);   // round-to-nearest-even
  return (u16)(u >> 16);
}

// async global->LDS, 16B per lane (m97 pattern)
#define GLD16(gp, lp) __builtin_amdgcn_global_load_lds( \
    (const __attribute__((address_space(1))) u32*)(gp), \
    (__attribute__((address_space(3))) u32*)(lp), 16, 0, 0)

#define VMC(n) asm volatile("s_waitcnt vmcnt(" #n ")" ::: "memory")
#define BARF() { asm volatile("" ::: "memory"); \
                 __builtin_amdgcn_s_barrier(); \
                 asm volatile("" ::: "memory"); }

// ---------------------------------------------------------------------------
// gemm_vv: V x V full-K GEMM for M = Wq^T * Wk (legacy R0 structure, proven).
// ---------------------------------------------------------------------------
__global__ void __launch_bounds__(256, 2)
gemm_vv(const u16* __restrict__ A, const u16* __restrict__ Bt, u16* __restrict__ C)
{
  int bn = blockIdx.x, bm = blockIdx.y;
  int m0 = bm * 128, n0 = bn * 128;

  __shared__ u16 As[128 * 64];
  __shared__ u16 Bs[128 * 64];

  int tid = threadIdx.x;
  int lane = tid & 63;
  int wid = tid >> 6;
  int wm = wid >> 1, wn = wid & 1;

  f32x4 acc[4][4] = {};

  int r0 = tid >> 3;
  int gcol = (((tid & 7) - r0) & 7) * 8;
  const u16* ga = A + (ll)(m0 + r0) * V_DIM + gcol;
  const u16* gb = Bt + (ll)(n0 + r0) * V_DIM + gcol;
  u16* la = As + tid * 8;
  u16* lb = Bs + tid * 8;
  const ll ld32 = (ll)32 * V_DIM;

  int rm = lane & 15;
  int q = lane >> 4;

  for (int k0 = 0; k0 < V_DIM; k0 += 64) {
#pragma unroll
    for (int i = 0; i < 4; i++) GLD16(ga + k0 + i * ld32, la + i * 2048);
#pragma unroll
    for (int i = 0; i < 4; i++) GLD16(gb + k0 + i * ld32, lb + i * 2048);
    __syncthreads();
#pragma unroll
    for (int ks = 0; ks < 2; ks++) {
      s16x8 af[4], bfv[4];
#pragma unroll
      for (int mi = 0; mi < 4; mi++) {
        int row = wm * 64 + mi * 16 + rm;
        int p = ((ks * 4 + q) + row) & 7;
        af[mi] = *(const s16x8*)&As[row * 64 + p * 8];
      }
#pragma unroll
      for (int ni = 0; ni < 4; ni++) {
        int row = wn * 64 + ni * 16 + rm;
        int p = ((ks * 4 + q) + row) & 7;
        bfv[ni] = *(const s16x8*)&Bs[row * 64 + p * 8];
      }
#pragma unroll
      for (int mi = 0; mi < 4; mi++)
#pragma unroll
        for (int ni = 0; ni < 4; ni++)
          acc[mi][ni] = __builtin_amdgcn_mfma_f32_16x16x32_bf16(
              af[mi], bfv[ni], acc[mi][ni], 0, 0, 0);
    }
    __syncthreads();
  }

  int col = lane & 15;
  int rq = (lane >> 4) * 4;
#pragma unroll
  for (int mi = 0; mi < 4; mi++)
#pragma unroll
    for (int ni = 0; ni < 4; ni++) {
      int lr = wm * 64 + mi * 16 + rq;
      int lc = wn * 64 + ni * 16 + col;
#pragma unroll
      for (int rr = 0; rr < 4; rr++)
        C[(ll)(m0 + lr + rr) * V_DIM + (n0 + lc)] = f2bf(acc[mi][ni][rr]);
    }
}

// ---------------------------------------------------------------------------
// gemm_br: 128x128-tile GEMM with B-operand in REGISTERS (no B LDS staging).
// C[m,n] = sum_k A[m,k]*Bt[n,k], bf16 in, fp32 accum. 4 waves (2x2), 64x64
// per wave, BK=64, 2 blocks/CU.
// Rationale: LDS traffic/CU/K-step drops 192KB -> 96KB (A stage 32 + A reads
// 64), raising the LDS-pipe ceiling from ~35% to ~MFMA-bound. B fragments are
// per-lane 16B global loads (16 rows x 64B segments, L2-served panels),
// double-buffered in named register arrays (static indexing), prefetched one
// K-tile ahead. A keeps R0's rotation-swizzled global_load_lds staging in a
// 2x16KB LDS dbuf. Per K-tile: issue A-stage(k+1)+B-loads(k+1), compute k,
// vmcnt(8) (drains A-stage only; B stays in flight), s_barrier.
// Accumulation order identical to R0 -> bit-identical output.
// MODE 1: A = tril(G * P^T), kmax=(bn+1)*128, bf16 out + tril mask, LPT
//   bn-desc (tau decode). MODE 2: out = A*Yt^T + bias, kmax=(bm+1)*128,
//   f32 out, LPT bm-desc. Grid assumes nb=8 (bz = lam&7).
// ---------------------------------------------------------------------------
template<int MODE>
__global__ void __launch_bounds__(256, 2)
gemm_br(const u16* __restrict__ Ag, int lda, ll batchA,
        const u16* __restrict__ Btg, int ldb, ll batchB,
        void* __restrict__ Cv, int ldc, ll batchC, float bias)
{
  int bn, bm, bz;
  if (MODE == 1) {
    int lam = blockIdx.x;
    int tau = lam >> 3; bz = lam & 7;
    int b = NT - 1, off = 0;                  // bn descending = heavy first
    while (tau >= off + (NT - b)) { off += NT - b; b--; }
    bn = b; bm = b + (tau - off);
  } else {
    int lam = blockIdx.x;
    bm = (NT - 1) - (lam >> 6);               // bm descending = heavy first
    bn = (lam >> 3) & 7;
    bz = lam & 7;
  }
  const u16* __restrict__ Ab = Ag + (ll)bz * batchA;
  const u16* __restrict__ Bb = Btg + (ll)bz * batchB;
  const int m0 = bm * 128, n0 = bn * 128;
  const int kmax = ((MODE == 1 ? bn : bm) + 1) * 128;
  const int nkt = kmax >> 6;                  // even, >= 2

  __shared__ u16 As[2][128 * 64];             // 2 x 16 KB

  const int tid = threadIdx.x;
  const int lane = tid & 63;
  const int wid = tid >> 6;
  const int wm = wid >> 1, wn = wid & 1;
  const int rm = lane & 15, q = lane >> 4;

  // A staging (rotation swizzle: slot p of row r holds chunk (p-r)&7)
  int r0 = tid >> 3;
  int gcol = (((tid & 7) - r0) & 7) * 8;
  const u16* ga = Ab + (ll)(m0 + r0) * lda + gcol;
  const ll lda32 = (ll)32 * lda;

  // B per-lane bases: frag(ni,ks) lane(rm,q) = Bt[n0+wn*64+ni*16+rm][k0+ks*32+q*8]
  const u16* gbn[4];
#pragma unroll
  for (int ni = 0; ni < 4; ni++)
    gbn[ni] = Bb + (ll)(n0 + wn * 64 + ni * 16 + rm) * ldb + q * 8;

  f32x4 acc[4][4] = {};
  s16x8 b0[2][4], b1[2][4];

#define STAGEA(buf, kt) { \
  _Pragma("unroll") for (int i = 0; i < 4; i++) \
    GLD16(ga + (kt) * 64 + i * lda32, &As[buf][0] + tid * 8 + i * 2048); }

#define LOADB(dst, kt) { \
  _Pragma("unroll") for (int ks = 0; ks < 2; ks++) \
    _Pragma("unroll") for (int ni = 0; ni < 4; ni++) \
      dst[ks][ni] = *(const s16x8*)(gbn[ni] + (kt) * 64 + ks * 32); }

#define COMPUTE(buf, bv) { \
  _Pragma("unroll") for (int ks = 0; ks < 2; ks++) { \
    s16x8 af[4]; \
    _Pragma("unroll") for (int mi = 0; mi < 4; mi++) { \
      int row = wm * 64 + mi * 16 + rm; \
      int p = ((ks * 4 + q) + row) & 7; \
      af[mi] = *(const s16x8*)&As[buf][row * 64 + p * 8]; \
    } \
    _Pragma("unroll") for (int mi = 0; mi < 4; mi++) \
      _Pragma("unroll") for (int ni = 0; ni < 4; ni++) \
        acc[mi][ni] = __builtin_amdgcn_mfma_f32_16x16x32_bf16( \
            af[mi], bv[ks][ni], acc[mi][ni], 0, 0, 0); \
  } }

  // prologue: tile 0 staged + B(0) loaded; one-time full drain
  STAGEA(0, 0); LOADB(b0, 0);
  __syncthreads();

  for (int kt = 0; kt < nkt; kt += 2) {
    // prep odd tile kt+1 (always exists: nkt even)
    STAGEA(1, kt + 1); LOADB(b1, kt + 1);
    COMPUTE(0, b0);                 // uses b0 (in flight since prev iter)
    VMC(8);                         // drain A-stage(kt+1); keep b1 in flight
    BARF();                         // seal As[1]
    const bool more = (kt + 2 < nkt);
    if (more) { STAGEA(0, kt + 2); LOADB(b0, kt + 2); }
    COMPUTE(1, b1);
    if (more) { VMC(8); BARF(); }   // drain A-stage(kt+2); seal As[0]
  }

  // epilogue
  const int col = lane & 15, rq = (lane >> 4) * 4;
#pragma unroll
  for (int mi = 0; mi < 4; mi++) {
#pragma unroll
    for (int ni = 0; ni < 4; ni++) {
      int lr = wm * 64 + mi * 16 + rq;
      int lc = wn * 64 + ni * 16 + col;
#pragma unroll
      for (int rr = 0; rr < 4; rr++) {
        float val = acc[mi][ni][rr];
        if (MODE == 1 && (n0 + lc) > (m0 + lr + rr)) val = 0.f;   // causal
        ll off = (ll)(m0 + lr + rr) * ldc + (n0 + lc);
        if (MODE == 2) {
          float* C = (float*)Cv + (ll)bz * batchC;
          C[off] = val + bias;
        } else {
          u16* C = (u16*)Cv + (ll)bz * batchC;
          C[off] = f2bf(val);
        }
      }
    }
  }
#undef STAGEA
#undef LOADB
#undef COMPUTE
}

// ---------------------------------------------------------------------------
// prep: z<2: transpose+cast VxV fp32 -> bf16 (dst[i][o]=src[o][i]);
//       z==2: straight cast of Wv
// ---------------------------------------------------------------------------
__global__ void prep_weights(const float* __restrict__ Wq, u16* __restrict__ WqT,
                             const float* __restrict__ Wk, u16* __restrict__ WkT,
                             const float* __restrict__ Wv, u16* __restrict__ Wvb)
{
  int z = blockIdx.z;
  if (z == 2) {
    int bx = blockIdx.y * 32 + blockIdx.x;
    int i = bx * 1024 + threadIdx.y * 32 + threadIdx.x;
#pragma unroll
    for (int k = 0; k < 4; k++) Wvb[i + k * 256] = f2bf(Wv[i + k * 256]);
    return;
  }
  const float* src = z ? Wk : Wq;
  u16* dst = z ? WkT : WqT;
  __shared__ float tile[32][33];
  int x0 = blockIdx.x * 32, y0 = blockIdx.y * 32;
  int tx = threadIdx.x, ty = threadIdx.y;
#pragma unroll
  for (int k = 0; k < 4; k++)
    tile[ty + k * 8][tx] = src[(ll)(y0 + ty + k * 8) * V_DIM + x0 + tx];
  __syncthreads();
#pragma unroll
  for (int k = 0; k < 4; k++)
    dst[(ll)(x0 + ty + k * 8) * V_DIM + y0 + tx] = f2bf(tile[tx][ty + k * 8]);
}

// P[s][u] = v[s-u] for u<=s else 0 (T x T bf16). Only the 128-block-tril
// region is ever read (gemm_br<1> reads u < (bn+1)*128 = roundup(s+1,128)),
// so skip stores above it (~halves the write traffic).
__global__ void build_p(const float* __restrict__ v, u16* __restrict__ P)
{
  int gid = blockIdx.x * 256 + threadIdx.x;
  int e0 = gid * 8;
  int s = e0 >> 11, u0 = e0 & 2047;
  int lim = ((s >> 7) + 1) << 7;
  if (u0 >= lim) return;
  s16x8 o;
#pragma unroll
  for (int k = 0; k < 8; k++) {
    int u = u0 + k;
    o[k] = (short)((u <= s) ? f2bf(v[s - u]) : (u16)0);
  }
  *(s16x8*)&P[e0] = o;
}

// merged gather: bx<T: G[z][t][u]=M[idx[t]][idx[u]] (tril 128-blocks only);
//                else Yt[z][j][s]=Wv[j][idx[s]]
__global__ void __launch_bounds__(256)
gather_gy(const int* __restrict__ idx, const u16* __restrict__ Mb,
          const u16* __restrict__ Wvb, u16* __restrict__ G,
          u16* __restrict__ Yt, int b0)
{
  int bx = blockIdx.x, z = blockIdx.y;
  const int* idxrow = idx + (ll)(b0 + z) * T_DIM;
  __shared__ u16 Row[V_DIM];
  int tid = threadIdx.x;
  const u32* src;
  u16* dst;
  int lim = T_DIM;
  if (bx < T_DIM) {
    src = (const u32*)(Mb + (ll)idxrow[bx] * V_DIM);
    dst = G + ((ll)z * T_DIM + bx) * T_DIM;
    lim = ((bx >> 7) + 1) << 7;    // gemm_br<1> reads G[t][u] only for u<lim
  } else {
    src = (const u32*)(Wvb + (ll)(bx - T_DIM) * V_DIM);
    dst = Yt + ((ll)z * V_DIM + (bx - T_DIM)) * T_DIM;
  }
  u32* dstl = (u32*)Row;
  dstl[tid] = src[tid];
  dstl[tid + 256] = src[tid + 256];
  __syncthreads();
  int s0 = tid * 8;
  if (s0 >= lim) return;
  int4 i0 = *(const int4*)&idxrow[s0];
  int4 i1 = *(const int4*)&idxrow[s0 + 4];
  s16x8 o;
  o[0] = (short)Row[i0.x]; o[1] = (short)Row[i0.y];
  o[2] = (short)Row[i0.z]; o[3] = (short)Row[i0.w];
  o[4] = (short)Row[i1.x]; o[5] = (short)Row[i1.y];
  o[6] = (short)Row[i1.z]; o[7] = (short)Row[i1.w];
  *(s16x8*)&dst[s0] = o;
}

// ---------------------------------------------------------------------------
extern "C" void kernel_launch(void* const* d_in, const int* in_sizes, int n_in,
                              void* d_out, int out_size, void* d_ws, size_t ws_size,
                              hipStream_t stream)
{
  const int*   idx = (const int*)d_in[0];
  const float* v   = (const float*)d_in[1];
  const float* Wk  = (const float*)d_in[2];
  const float* Wq  = (const float*)d_in[3];
  const float* Wv  = (const float*)d_in[4];
  float* out = (float*)d_out;

  char* p = (char*)d_ws;
  const size_t SZ_VV = (size_t)V_DIM * V_DIM * 2;   // 2 MB bf16
  const size_t SZ_TT = (size_t)T_DIM * T_DIM * 2;   // 8 MB bf16
  const size_t SZ_VT = (size_t)V_DIM * T_DIM * 2;   // 4 MB bf16
  u16* WqT = (u16*)p; p += SZ_VV;
  u16* WkT = (u16*)p; p += SZ_VV;
  u16* Wvb = (u16*)p; p += SZ_VV;
  u16* Mb  = (u16*)p; p += SZ_VV;
  u16* P   = (u16*)p; p += SZ_TT;
  size_t used = (size_t)(p - (char*)d_ws);
  size_t per = 2 * SZ_TT + SZ_VT;                    // G + A + Yt per batch
  int nb = 8;
  while (nb > 1 && used + (size_t)nb * per > ws_size) nb >>= 1;
  u16* G    = (u16*)p; p += (size_t)nb * SZ_TT;
  u16* Abuf = (u16*)p; p += (size_t)nb * SZ_TT;
  u16* Yt   = (u16*)p;

  prep_weights<<<dim3(32, 32, 3), dim3(32, 8), 0, stream>>>(Wq, WqT, Wk, WkT, Wv, Wvb);
  build_p<<<2048, 256, 0, stream>>>(v, P);
  // M = Wq^T * Wk  [V,V]
  gemm_vv<<<dim3(V_DIM / 128, V_DIM / 128, 1), 256, 0, stream>>>(WqT, WkT, Mb);

  for (int b0 = 0; b0 < B_DIM; b0 += nb) {
    gather_gy<<<dim3(T_DIM + V_DIM, nb), 256, 0, stream>>>(idx, Mb, Wvb, G, Yt, b0);
    // A = tril(G * P^T): 136 tril tiles x nb, bn-desc LPT, B(=P) in registers
    gemm_br<1><<<dim3(nb * 136, 1, 1), 256, 0, stream>>>(
        G, T_DIM, (ll)T_DIM * T_DIM, P, T_DIM, 0,
        Abuf, T_DIM, (ll)T_DIM * T_DIM, 0.f);
    // out = A * Yt^T + 0.001: causal-K, bm-desc LPT, B(=Yt) in registers
    gemm_br<2><<<dim3((V_DIM / 128) * nb * NT, 1, 1), 256, 0, stream>>>(
        Abuf, T_DIM, (ll)T_DIM * T_DIM, Yt, T_DIM, (ll)V_DIM * T_DIM,
        out + (ll)b0 * T_DIM * V_DIM, V_DIM, (ll)T_DIM * V_DIM,
        0.001f);
  }
}

// Round 5
// 199.158 us; speedup vs baseline: 1.4019x; 1.3763x over previous
//
#include <hip/hip_runtime.h>
#include <stdint.h>

#define T_DIM 2048
#define V_DIM 1024
#define B_DIM 8
#define NT 16            // T_DIM/128

typedef unsigned int u32;
typedef unsigned short u16;
typedef long long ll;
typedef __attribute__((ext_vector_type(8))) short s16x8;
typedef __attribute__((ext_vector_type(4))) float f32x4;

__device__ __forceinline__ u16 f2bf(float x) {
  u32 u = __builtin_bit_cast(u32, x);
  u = u + 0x7FFFu + ((u >> 16) & 1u);   // round-to-nearest-even
  return (u16)(u >> 16);
}

// async global->LDS, 16B per lane (m97 pattern)
#define GLD16(gp, lp) __builtin_amdgcn_global_load_lds( \
    (const __attribute__((address_space(1))) u32*)(gp), \
    (__attribute__((address_space(3))) u32*)(lp), 16, 0, 0)

// ---------------------------------------------------------------------------
// gemm_bt: EXACT R0 structure (proven 45 us / ~810 TF; do not touch).
// C[m,n] = sum_k A[m,k] * Bt[n,k]   (bf16 row-major, fp32 accum)
// 128x128 tile, BK=64, 256 threads = 4 waves (2x2), each wave 64x64.
// Rotation swizzle: physical slot p of row r holds logical chunk (p-r)&7 ->
// ds_read_b128 conflict-free (verified SQ_LDS_BANK_CONFLICT=0).
// MODE 0: plain; grid (N/128, M/128, nz).
// MODE 1: tril(A) out, T x T. grid (1088): tau=lam>>3 (bn-DESC = LPT),
//         bz=lam&7; kmax=(bn+1)*128; epilogue masks gc>gr.
// MODE 2: causal-K, kmax=(bm+1)*128. grid (1024): bm=15-(lam>>6) (LPT),
//         n=(lam>>3)&7, bz=lam&7.
// F32OUT: write float + bias, else bf16.
// ---------------------------------------------------------------------------
template<int MODE, bool F32OUT>
__global__ void __launch_bounds__(256, 2)
gemm_bt(const u16* __restrict__ A, int lda, ll batchA,
        const u16* __restrict__ Bt, int ldb, ll batchB,
        void* __restrict__ Cv, int ldc, ll batchC,
        int K, float bias)
{
  int bn, bm, bz;
  if (MODE == 0) {
    bn = blockIdx.x; bm = blockIdx.y; bz = blockIdx.z;
  } else if (MODE == 1) {
    int lam = blockIdx.x;
    int tau = lam >> 3; bz = lam & 7;
    int b = NT - 1, off = 0;                  // bn descending (heavy first)
    while (tau >= off + (NT - b)) { off += NT - b; b--; }
    bn = b; bm = b + (tau - off);
  } else {                                    // MODE 2
    int lam = blockIdx.x;
    bm = (NT - 1) - (lam >> 6);               // heavy first (LPT)
    bn = (lam >> 3) & 7;
    bz = lam & 7;
  }
  const u16* Ab = A + (ll)bz * batchA;
  const u16* Bb = Bt + (ll)bz * batchB;
  int m0 = bm * 128, n0 = bn * 128;
  int kmax = K;
  if (MODE == 1) { int kl = (bn + 1) * 128; kmax = kl < K ? kl : K; }
  if (MODE == 2) { int kl = (bm + 1) * 128; kmax = kl < K ? kl : K; }

  __shared__ u16 As[128 * 64];   // 16 KB
  __shared__ u16 Bs[128 * 64];   // 16 KB

  int tid = threadIdx.x;
  int lane = tid & 63;
  int wid = tid >> 6;
  int wm = wid >> 1, wn = wid & 1;

  f32x4 acc[4][4] = {};

  int r0 = tid >> 3;
  int gcol = (((tid & 7) - r0) & 7) * 8;
  const u16* ga = Ab + (ll)(m0 + r0) * lda + gcol;
  const u16* gb = Bb + (ll)(n0 + r0) * ldb + gcol;
  u16* la = As + tid * 8;        // byte offset tid*16 (wave-contiguous)
  u16* lb = Bs + tid * 8;
  ll lda32 = (ll)32 * lda;
  ll ldb32 = (ll)32 * ldb;

  int rm = lane & 15;
  int q = lane >> 4;

  for (int k0 = 0; k0 < kmax; k0 += 64) {
#pragma unroll
    for (int i = 0; i < 4; i++)
      GLD16(ga + k0 + i * lda32, la + i * 2048);
#pragma unroll
    for (int i = 0; i < 4; i++)
      GLD16(gb + k0 + i * ldb32, lb + i * 2048);
    __syncthreads();
#pragma unroll
    for (int ks = 0; ks < 2; ks++) {
      s16x8 af[4], bfv[4];
#pragma unroll
      for (int mi = 0; mi < 4; mi++) {
        int row = wm * 64 + mi * 16 + rm;
        int p = ((ks * 4 + q) + row) & 7;
        af[mi] = *(const s16x8*)&As[row * 64 + p * 8];
      }
#pragma unroll
      for (int ni = 0; ni < 4; ni++) {
        int row = wn * 64 + ni * 16 + rm;
        int p = ((ks * 4 + q) + row) & 7;
        bfv[ni] = *(const s16x8*)&Bs[row * 64 + p * 8];
      }
#pragma unroll
      for (int mi = 0; mi < 4; mi++)
#pragma unroll
        for (int ni = 0; ni < 4; ni++)
          acc[mi][ni] = __builtin_amdgcn_mfma_f32_16x16x32_bf16(
              af[mi], bfv[ni], acc[mi][ni], 0, 0, 0);
    }
    __syncthreads();
  }

  // C/D layout (m89-verified): col = lane&15, row = (lane>>4)*4 + reg
  int col = lane & 15;
  int rq = (lane >> 4) * 4;
#pragma unroll
  for (int mi = 0; mi < 4; mi++) {
#pragma unroll
    for (int ni = 0; ni < 4; ni++) {
      int lr = wm * 64 + mi * 16 + rq;          // local row (base of 4)
      int lc = wn * 64 + ni * 16 + col;         // local col
#pragma unroll
      for (int rr = 0; rr < 4; rr++) {
        float val = acc[mi][ni][rr];
        if (MODE == 1 && (n0 + lc) > (m0 + lr + rr)) val = 0.f;  // causal
        ll off = (ll)(m0 + lr + rr) * ldc + (n0 + lc);
        if (F32OUT) {
          float* C = (float*)Cv + (ll)bz * batchC;
          C[off] = val + bias;
        } else {
          u16* C = (u16*)Cv + (ll)bz * batchC;
          C[off] = f2bf(val);
        }
      }
    }
  }
}

// ---------------------------------------------------------------------------
// prep: z<2: transpose+cast VxV fp32 -> bf16 (dst[i][o]=src[o][i]);
//       z==2: straight cast of Wv
// ---------------------------------------------------------------------------
__global__ void prep_weights(const float* __restrict__ Wq, u16* __restrict__ WqT,
                             const float* __restrict__ Wk, u16* __restrict__ WkT,
                             const float* __restrict__ Wv, u16* __restrict__ Wvb)
{
  int z = blockIdx.z;
  if (z == 2) {
    int bx = blockIdx.y * 32 + blockIdx.x;
    int i = bx * 1024 + threadIdx.y * 32 + threadIdx.x;
#pragma unroll
    for (int k = 0; k < 4; k++) Wvb[i + k * 256] = f2bf(Wv[i + k * 256]);
    return;
  }
  const float* src = z ? Wk : Wq;
  u16* dst = z ? WkT : WqT;
  __shared__ float tile[32][33];
  int x0 = blockIdx.x * 32, y0 = blockIdx.y * 32;
  int tx = threadIdx.x, ty = threadIdx.y;
#pragma unroll
  for (int k = 0; k < 4; k++)
    tile[ty + k * 8][tx] = src[(ll)(y0 + ty + k * 8) * V_DIM + x0 + tx];
  __syncthreads();
#pragma unroll
  for (int k = 0; k < 4; k++)
    dst[(ll)(x0 + ty + k * 8) * V_DIM + y0 + tx] = f2bf(tile[tx][ty + k * 8]);
}

// P[s][u] = v[s-u] for u<=s else 0 (T x T bf16). gemm<1> (B-operand) reads
// row s only for u < ((s>>7)+1)*128, so skip stores above that (verified R4).
__global__ void build_p(const float* __restrict__ v, u16* __restrict__ P)
{
  int gid = blockIdx.x * 256 + threadIdx.x;
  int e0 = gid * 8;
  int s = e0 >> 11, u0 = e0 & 2047;
  int lim = ((s >> 7) + 1) << 7;
  if (u0 >= lim) return;
  s16x8 o;
#pragma unroll
  for (int k = 0; k < 8; k++) {
    int u = u0 + k;
    o[k] = (short)((u <= s) ? f2bf(v[s - u]) : (u16)0);
  }
  *(s16x8*)&P[e0] = o;
}

// ---------------------------------------------------------------------------
// gather_gy v2: 8 rows per block (idx row staged to LDS ONCE per 8 rows;
// source rows staged via 4 async global_load_lds passes).
//   bx < 256 : G[z][t0+r][u] = M[idx[t0+r]][idx[u]], t0=bx*8,
//              only u < ((t>>7)+1)*128 (gemm<1> A-operand read bound, R4-verified)
//   bx >= 256: Yt[z][j0+r][s] = Wv[j0+r][idx[s]], j0=(bx-256)*8
// ---------------------------------------------------------------------------
__global__ void __launch_bounds__(256)
gather_gy(const int* __restrict__ idx, const u16* __restrict__ Mb,
          const u16* __restrict__ Wvb, u16* __restrict__ G,
          u16* __restrict__ Yt, int b0)
{
  int bx = blockIdx.x, z = blockIdx.y;
  const int* idxrow = idx + (ll)(b0 + z) * T_DIM;
  __shared__ u16 Rows[8 * V_DIM];   // 16 KB: 8 staged source rows
  __shared__ int icol[T_DIM];       // 8 KB: gather indices
  int tid = threadIdx.x;
  const bool isG = (bx < 256);
  int t0 = bx * 8;                  // G: first t-row
  int j0 = (bx - 256) * 8;          // Yt: first j-row

  // stage idx cols (2048 ints) to LDS: 8 ints/thread
  {
    int4 a = ((const int4*)idxrow)[tid * 2];
    int4 b = ((const int4*)idxrow)[tid * 2 + 1];
    ((int4*)icol)[tid * 2] = a;
    ((int4*)icol)[tid * 2 + 1] = b;
  }

  // stage 8 source rows, 2 per pass: thread -> row 2p+(tid>>7), 16B chunk tid&127
#pragma unroll
  for (int p = 0; p < 4; p++) {
    int r = 2 * p + (tid >> 7);
    const u16* src;
    if (isG) src = Mb + (ll)idxrow[t0 + r] * V_DIM + (tid & 127) * 8;
    else     src = Wvb + (ll)(j0 + r) * V_DIM + (tid & 127) * 8;
    GLD16(src, &Rows[p * 2048 + tid * 8]);
  }
  __syncthreads();   // drains vmcnt + lgkm before barrier (compiler-inserted)

  int s0 = tid * 8;
#pragma unroll
  for (int r = 0; r < 8; r++) {
    int lim = isG ? ((((t0 + r) >> 7) + 1) << 7) : T_DIM;
    if (s0 < lim) {
      const u16* Row = &Rows[r * V_DIM];
      int4 i0 = *(const int4*)&icol[s0];
      int4 i1 = *(const int4*)&icol[s0 + 4];
      s16x8 o;
      o[0] = (short)Row[i0.x]; o[1] = (short)Row[i0.y];
      o[2] = (short)Row[i0.z]; o[3] = (short)Row[i0.w];
      o[4] = (short)Row[i1.x]; o[5] = (short)Row[i1.y];
      o[6] = (short)Row[i1.z]; o[7] = (short)Row[i1.w];
      u16* dst = isG ? (G + ((ll)z * T_DIM + t0 + r) * T_DIM)
                     : (Yt + ((ll)z * V_DIM + j0 + r) * T_DIM);
      *(s16x8*)&dst[s0] = o;
    }
  }
}

// ---------------------------------------------------------------------------
extern "C" void kernel_launch(void* const* d_in, const int* in_sizes, int n_in,
                              void* d_out, int out_size, void* d_ws, size_t ws_size,
                              hipStream_t stream)
{
  const int*   idx = (const int*)d_in[0];
  const float* v   = (const float*)d_in[1];
  const float* Wk  = (const float*)d_in[2];
  const float* Wq  = (const float*)d_in[3];
  const float* Wv  = (const float*)d_in[4];
  float* out = (float*)d_out;

  char* p = (char*)d_ws;
  const size_t SZ_VV = (size_t)V_DIM * V_DIM * 2;   // 2 MB bf16
  const size_t SZ_TT = (size_t)T_DIM * T_DIM * 2;   // 8 MB bf16
  const size_t SZ_VT = (size_t)V_DIM * T_DIM * 2;   // 4 MB bf16
  u16* WqT = (u16*)p; p += SZ_VV;
  u16* WkT = (u16*)p; p += SZ_VV;
  u16* Wvb = (u16*)p; p += SZ_VV;
  u16* Mb  = (u16*)p; p += SZ_VV;
  u16* P   = (u16*)p; p += SZ_TT;
  size_t used = (size_t)(p - (char*)d_ws);
  size_t per = 2 * SZ_TT + SZ_VT;                    // G + A + Yt per batch
  int nb = 8;
  while (nb > 1 && used + (size_t)nb * per > ws_size) nb >>= 1;
  u16* G    = (u16*)p; p += (size_t)nb * SZ_TT;
  u16* Abuf = (u16*)p; p += (size_t)nb * SZ_TT;
  u16* Yt   = (u16*)p;

  prep_weights<<<dim3(32, 32, 3), dim3(32, 8), 0, stream>>>(Wq, WqT, Wk, WkT, Wv, Wvb);
  build_p<<<2048, 256, 0, stream>>>(v, P);
  // M = Wq^T * Wk  [V,V]
  gemm_bt<0, false><<<dim3(V_DIM / 128, V_DIM / 128, 1), 256, 0, stream>>>(
      WqT, V_DIM, 0, WkT, V_DIM, 0, Mb, V_DIM, 0, V_DIM, 0.f);

  for (int b0 = 0; b0 < B_DIM; b0 += nb) {
    gather_gy<<<dim3(256 + 128, nb), 256, 0, stream>>>(idx, Mb, Wvb, G, Yt, b0);
    // A = tril(G * P^T): 136 tril tiles x nb, bn-desc LPT
    gemm_bt<1, false><<<dim3(nb * 136, 1, 1), 256, 0, stream>>>(
        G, T_DIM, (ll)T_DIM * T_DIM, P, T_DIM, 0,
        Abuf, T_DIM, (ll)T_DIM * T_DIM, T_DIM, 0.f);
    // out = A * Yt^T + 0.001, causal-K, bm-desc LPT
    gemm_bt<2, true><<<dim3((V_DIM / 128) * nb * NT, 1, 1), 256, 0, stream>>>(
        Abuf, T_DIM, (ll)T_DIM * T_DIM, Yt, T_DIM, (ll)V_DIM * T_DIM,
        out + (ll)b0 * T_DIM * V_DIM, V_DIM, (ll)T_DIM * V_DIM,
        T_DIM, 0.001f);
  }
}

// Round 6
// 195.503 us; speedup vs baseline: 1.4282x; 1.0187x over previous
//
#include <hip/hip_runtime.h>
#include <stdint.h>

#define T_DIM 2048
#define V_DIM 1024
#define B_DIM 8
#define NT 16            // T_DIM/128

typedef unsigned int u32;
typedef unsigned short u16;
typedef long long ll;
typedef __attribute__((ext_vector_type(8))) short s16x8;
typedef __attribute__((ext_vector_type(4))) float f32x4;

__device__ __forceinline__ u16 f2bf(float x) {
  u32 u = __builtin_bit_cast(u32, x);
  u = u + 0x7FFFu + ((u >> 16) & 1u);   // round-to-nearest-even
  return (u16)(u >> 16);
}

// async global->LDS, 16B per lane (m97 pattern)
#define GLD16(gp, lp) __builtin_amdgcn_global_load_lds( \
    (const __attribute__((address_space(1))) u32*)(gp), \
    (__attribute__((address_space(3))) u32*)(lp), 16, 0, 0)

// ---------------------------------------------------------------------------
// gemm_bt: EXACT R0 structure (proven 45 us / ~810 TF; shape-floor: work-
// limit 36.5GF/810TF = 45us == tail-limit 67MF/1.6TF = 42us. Do not touch.)
// C[m,n] = sum_k A[m,k] * Bt[n,k]   (bf16 row-major, fp32 accum)
// 128x128 tile, BK=64, 256 threads = 4 waves (2x2), each wave 64x64.
// Rotation swizzle: physical slot p of row r holds logical chunk (p-r)&7 ->
// ds_read_b128 conflict-free (verified SQ_LDS_BANK_CONFLICT=0).
// MODE 1: tril(A) out, T x T. grid (1088): tau=lam>>3 (bn-DESC = LPT),
//         bz=lam&7; kmax=(bn+1)*128; epilogue masks gc>gr.
// MODE 2: causal-K, kmax=(bm+1)*128. grid (1024): bm=15-(lam>>6) (LPT),
//         n=(lam>>3)&7, bz=lam&7.
// F32OUT: write float + bias, else bf16.
// ---------------------------------------------------------------------------
template<int MODE, bool F32OUT>
__global__ void __launch_bounds__(256, 2)
gemm_bt(const u16* __restrict__ A, int lda, ll batchA,
        const u16* __restrict__ Bt, int ldb, ll batchB,
        void* __restrict__ Cv, int ldc, ll batchC,
        int K, float bias)
{
  int bn, bm, bz;
  if (MODE == 1) {
    int lam = blockIdx.x;
    int tau = lam >> 3; bz = lam & 7;
    int b = NT - 1, off = 0;                  // bn descending (heavy first)
    while (tau >= off + (NT - b)) { off += NT - b; b--; }
    bn = b; bm = b + (tau - off);
  } else {                                    // MODE 2
    int lam = blockIdx.x;
    bm = (NT - 1) - (lam >> 6);               // heavy first (LPT)
    bn = (lam >> 3) & 7;
    bz = lam & 7;
  }
  const u16* Ab = A + (ll)bz * batchA;
  const u16* Bb = Bt + (ll)bz * batchB;
  int m0 = bm * 128, n0 = bn * 128;
  int kmax = K;
  if (MODE == 1) { int kl = (bn + 1) * 128; kmax = kl < K ? kl : K; }
  if (MODE == 2) { int kl = (bm + 1) * 128; kmax = kl < K ? kl : K; }

  __shared__ u16 As[128 * 64];   // 16 KB
  __shared__ u16 Bs[128 * 64];   // 16 KB

  int tid = threadIdx.x;
  int lane = tid & 63;
  int wid = tid >> 6;
  int wm = wid >> 1, wn = wid & 1;

  f32x4 acc[4][4] = {};

  int r0 = tid >> 3;
  int gcol = (((tid & 7) - r0) & 7) * 8;
  const u16* ga = Ab + (ll)(m0 + r0) * lda + gcol;
  const u16* gb = Bb + (ll)(n0 + r0) * ldb + gcol;
  u16* la = As + tid * 8;        // byte offset tid*16 (wave-contiguous)
  u16* lb = Bs + tid * 8;
  ll lda32 = (ll)32 * lda;
  ll ldb32 = (ll)32 * ldb;

  int rm = lane & 15;
  int q = lane >> 4;

  for (int k0 = 0; k0 < kmax; k0 += 64) {
#pragma unroll
    for (int i = 0; i < 4; i++)
      GLD16(ga + k0 + i * lda32, la + i * 2048);
#pragma unroll
    for (int i = 0; i < 4; i++)
      GLD16(gb + k0 + i * ldb32, lb + i * 2048);
    __syncthreads();
#pragma unroll
    for (int ks = 0; ks < 2; ks++) {
      s16x8 af[4], bfv[4];
#pragma unroll
      for (int mi = 0; mi < 4; mi++) {
        int row = wm * 64 + mi * 16 + rm;
        int p = ((ks * 4 + q) + row) & 7;
        af[mi] = *(const s16x8*)&As[row * 64 + p * 8];
      }
#pragma unroll
      for (int ni = 0; ni < 4; ni++) {
        int row = wn * 64 + ni * 16 + rm;
        int p = ((ks * 4 + q) + row) & 7;
        bfv[ni] = *(const s16x8*)&Bs[row * 64 + p * 8];
      }
#pragma unroll
      for (int mi = 0; mi < 4; mi++)
#pragma unroll
        for (int ni = 0; ni < 4; ni++)
          acc[mi][ni] = __builtin_amdgcn_mfma_f32_16x16x32_bf16(
              af[mi], bfv[ni], acc[mi][ni], 0, 0, 0);
    }
    __syncthreads();
  }

  // C/D layout (m89-verified): col = lane&15, row = (lane>>4)*4 + reg
  int col = lane & 15;
  int rq = (lane >> 4) * 4;
#pragma unroll
  for (int mi = 0; mi < 4; mi++) {
#pragma unroll
    for (int ni = 0; ni < 4; ni++) {
      int lr = wm * 64 + mi * 16 + rq;          // local row (base of 4)
      int lc = wn * 64 + ni * 16 + col;         // local col
#pragma unroll
      for (int rr = 0; rr < 4; rr++) {
        float val = acc[mi][ni][rr];
        if (MODE == 1 && (n0 + lc) > (m0 + lr + rr)) val = 0.f;  // causal
        ll off = (ll)(m0 + lr + rr) * ldc + (n0 + lc);
        if (F32OUT) {
          float* C = (float*)Cv + (ll)bz * batchC;
          C[off] = val + bias;
        } else {
          u16* C = (u16*)Cv + (ll)bz * batchC;
          C[off] = f2bf(val);
        }
      }
    }
  }
}

// ---------------------------------------------------------------------------
// gemm_vv64: M = Wq^T * Wk (V x V, K=V) on 64x64 tiles, 4 waves of 32x32.
// grid 16x16 = 256 blocks -> all 256 CUs busy (the old 8x8=64-block version
// left 192 CUs idle and was latency-exposed: ~20 us for 2.1 GF).
// Same schedule/swizzle/K-order as gemm_bt -> Mb bit-identical.
// ---------------------------------------------------------------------------
__global__ void __launch_bounds__(256, 2)
gemm_vv64(const u16* __restrict__ A, const u16* __restrict__ Bt,
          u16* __restrict__ C)
{
  int bn = blockIdx.x, bm = blockIdx.y;
  int m0 = bm * 64, n0 = bn * 64;

  __shared__ u16 As[64 * 64];   // 8 KB
  __shared__ u16 Bs[64 * 64];   // 8 KB

  int tid = threadIdx.x;
  int lane = tid & 63;
  int wid = tid >> 6;
  int wm = wid >> 1, wn = wid & 1;

  f32x4 acc[2][2] = {};

  int r0 = tid >> 3;                 // 0..31 (pass stride 32 rows)
  int gcol = (((tid & 7) - r0) & 7) * 8;
  const u16* ga = A + (ll)(m0 + r0) * V_DIM + gcol;
  const u16* gb = Bt + (ll)(n0 + r0) * V_DIM + gcol;
  u16* la = As + tid * 8;
  u16* lb = Bs + tid * 8;
  const ll ld32 = (ll)32 * V_DIM;

  int rm = lane & 15;
  int q = lane >> 4;

  for (int k0 = 0; k0 < V_DIM; k0 += 64) {
#pragma unroll
    for (int i = 0; i < 2; i++) GLD16(ga + k0 + i * ld32, la + i * 2048);
#pragma unroll
    for (int i = 0; i < 2; i++) GLD16(gb + k0 + i * ld32, lb + i * 2048);
    __syncthreads();
#pragma unroll
    for (int ks = 0; ks < 2; ks++) {
      s16x8 af[2], bfv[2];
#pragma unroll
      for (int mi = 0; mi < 2; mi++) {
        int row = wm * 32 + mi * 16 + rm;
        int p = ((ks * 4 + q) + row) & 7;
        af[mi] = *(const s16x8*)&As[row * 64 + p * 8];
      }
#pragma unroll
      for (int ni = 0; ni < 2; ni++) {
        int row = wn * 32 + ni * 16 + rm;
        int p = ((ks * 4 + q) + row) & 7;
        bfv[ni] = *(const s16x8*)&Bs[row * 64 + p * 8];
      }
#pragma unroll
      for (int mi = 0; mi < 2; mi++)
#pragma unroll
        for (int ni = 0; ni < 2; ni++)
          acc[mi][ni] = __builtin_amdgcn_mfma_f32_16x16x32_bf16(
              af[mi], bfv[ni], acc[mi][ni], 0, 0, 0);
    }
    __syncthreads();
  }

  int col = lane & 15;
  int rq = (lane >> 4) * 4;
#pragma unroll
  for (int mi = 0; mi < 2; mi++)
#pragma unroll
    for (int ni = 0; ni < 2; ni++) {
      int lr = wm * 32 + mi * 16 + rq;
      int lc = wn * 32 + ni * 16 + col;
#pragma unroll
      for (int rr = 0; rr < 4; rr++)
        C[(ll)(m0 + lr + rr) * V_DIM + (n0 + lc)] = f2bf(acc[mi][ni][rr]);
    }
}

// ---------------------------------------------------------------------------
// prep_all: merged prep_weights + build_p (one node fewer).
// bid < 3072: z = bid>>10 — z<2: transpose+cast VxV fp32->bf16; z==2: cast Wv.
// bid >= 3072: build_p: P[s][u] = v[s-u] for u<=s else 0, stores only
//   u < ((s>>7)+1)*128 (gemm_bt<1> read bound, R4/R5-verified).
// ---------------------------------------------------------------------------
__global__ void __launch_bounds__(256)
prep_all(const float* __restrict__ Wq, u16* __restrict__ WqT,
         const float* __restrict__ Wk, u16* __restrict__ WkT,
         const float* __restrict__ Wv, u16* __restrict__ Wvb,
         const float* __restrict__ v, u16* __restrict__ P)
{
  int bid = blockIdx.x;
  int tid = threadIdx.x;
  if (bid >= 3072) {                 // ---- build_p part ----
    int gid = (bid - 3072) * 256 + tid;
    int e0 = gid * 8;
    int s = e0 >> 11, u0 = e0 & 2047;
    int lim = ((s >> 7) + 1) << 7;
    if (u0 >= lim) return;
    s16x8 o;
#pragma unroll
    for (int k = 0; k < 8; k++) {
      int u = u0 + k;
      o[k] = (short)((u <= s) ? f2bf(v[s - u]) : (u16)0);
    }
    *(s16x8*)&P[e0] = o;
    return;
  }
  int z = bid >> 10, within = bid & 1023;
  if (z == 2) {                      // ---- straight cast of Wv ----
    int i = within * 1024 + tid;
#pragma unroll
    for (int k = 0; k < 4; k++) Wvb[i + k * 256] = f2bf(Wv[i + k * 256]);
    return;
  }
  const float* src = z ? Wk : Wq;    // ---- transpose+cast ----
  u16* dst = z ? WkT : WqT;
  __shared__ float tile[32][33];
  int bx = within & 31, by = within >> 5;
  int x0 = bx * 32, y0 = by * 32;
  int tx = tid & 31, ty = tid >> 5;
#pragma unroll
  for (int k = 0; k < 4; k++)
    tile[ty + k * 8][tx] = src[(ll)(y0 + ty + k * 8) * V_DIM + x0 + tx];
  __syncthreads();
#pragma unroll
  for (int k = 0; k < 4; k++)
    dst[(ll)(x0 + ty + k * 8) * V_DIM + y0 + tx] = f2bf(tile[tx][ty + k * 8]);
}

// ---------------------------------------------------------------------------
// gather_gy v2: 8 rows per block (idx row staged to LDS ONCE per 8 rows;
// source rows staged via 4 async global_load_lds passes).
//   bx < 256 : G[z][t0+r][u] = M[idx[t0+r]][idx[u]], t0=bx*8,
//              only u < ((t>>7)+1)*128 (gemm<1> A-operand read bound)
//   bx >= 256: Yt[z][j0+r][s] = Wv[j0+r][idx[s]], j0=(bx-256)*8
// ---------------------------------------------------------------------------
__global__ void __launch_bounds__(256)
gather_gy(const int* __restrict__ idx, const u16* __restrict__ Mb,
          const u16* __restrict__ Wvb, u16* __restrict__ G,
          u16* __restrict__ Yt, int b0)
{
  int bx = blockIdx.x, z = blockIdx.y;
  const int* idxrow = idx + (ll)(b0 + z) * T_DIM;
  __shared__ u16 Rows[8 * V_DIM];   // 16 KB: 8 staged source rows
  __shared__ int icol[T_DIM];       // 8 KB: gather indices
  int tid = threadIdx.x;
  const bool isG = (bx < 256);
  int t0 = bx * 8;                  // G: first t-row
  int j0 = (bx - 256) * 8;          // Yt: first j-row

  // stage idx cols (2048 ints) to LDS: 8 ints/thread
  {
    int4 a = ((const int4*)idxrow)[tid * 2];
    int4 b = ((const int4*)idxrow)[tid * 2 + 1];
    ((int4*)icol)[tid * 2] = a;
    ((int4*)icol)[tid * 2 + 1] = b;
  }

  // stage 8 source rows, 2 per pass: thread -> row 2p+(tid>>7), 16B chunk tid&127
#pragma unroll
  for (int p = 0; p < 4; p++) {
    int r = 2 * p + (tid >> 7);
    const u16* src;
    if (isG) src = Mb + (ll)idxrow[t0 + r] * V_DIM + (tid & 127) * 8;
    else     src = Wvb + (ll)(j0 + r) * V_DIM + (tid & 127) * 8;
    GLD16(src, &Rows[p * 2048 + tid * 8]);
  }
  __syncthreads();   // drains vmcnt + lgkm before barrier (compiler-inserted)

  int s0 = tid * 8;
#pragma unroll
  for (int r = 0; r < 8; r++) {
    int lim = isG ? ((((t0 + r) >> 7) + 1) << 7) : T_DIM;
    if (s0 < lim) {
      const u16* Row = &Rows[r * V_DIM];
      int4 i0 = *(const int4*)&icol[s0];
      int4 i1 = *(const int4*)&icol[s0 + 4];
      s16x8 o;
      o[0] = (short)Row[i0.x]; o[1] = (short)Row[i0.y];
      o[2] = (short)Row[i0.z]; o[3] = (short)Row[i0.w];
      o[4] = (short)Row[i1.x]; o[5] = (short)Row[i1.y];
      o[6] = (short)Row[i1.z]; o[7] = (short)Row[i1.w];
      u16* dst = isG ? (G + ((ll)z * T_DIM + t0 + r) * T_DIM)
                     : (Yt + ((ll)z * V_DIM + j0 + r) * T_DIM);
      *(s16x8*)&dst[s0] = o;
    }
  }
}

// ---------------------------------------------------------------------------
extern "C" void kernel_launch(void* const* d_in, const int* in_sizes, int n_in,
                              void* d_out, int out_size, void* d_ws, size_t ws_size,
                              hipStream_t stream)
{
  const int*   idx = (const int*)d_in[0];
  const float* v   = (const float*)d_in[1];
  const float* Wk  = (const float*)d_in[2];
  const float* Wq  = (const float*)d_in[3];
  const float* Wv  = (const float*)d_in[4];
  float* out = (float*)d_out;

  char* p = (char*)d_ws;
  const size_t SZ_VV = (size_t)V_DIM * V_DIM * 2;   // 2 MB bf16
  const size_t SZ_TT = (size_t)T_DIM * T_DIM * 2;   // 8 MB bf16
  const size_t SZ_VT = (size_t)V_DIM * T_DIM * 2;   // 4 MB bf16
  u16* WqT = (u16*)p; p += SZ_VV;
  u16* WkT = (u16*)p; p += SZ_VV;
  u16* Wvb = (u16*)p; p += SZ_VV;
  u16* Mb  = (u16*)p; p += SZ_VV;
  u16* P   = (u16*)p; p += SZ_TT;
  size_t used = (size_t)(p - (char*)d_ws);
  size_t per = 2 * SZ_TT + SZ_VT;                    // G + A + Yt per batch
  int nb = 8;
  while (nb > 1 && used + (size_t)nb * per > ws_size) nb >>= 1;
  u16* G    = (u16*)p; p += (size_t)nb * SZ_TT;
  u16* Abuf = (u16*)p; p += (size_t)nb * SZ_TT;
  u16* Yt   = (u16*)p;

  // prep + build_p merged (one node)
  prep_all<<<dim3(3072 + 2048), 256, 0, stream>>>(Wq, WqT, Wk, WkT, Wv, Wvb, v, P);
  // M = Wq^T * Wk  [V,V] on 64x64 tiles (256 blocks -> full GPU)
  gemm_vv64<<<dim3(16, 16), 256, 0, stream>>>(WqT, WkT, Mb);

  for (int b0 = 0; b0 < B_DIM; b0 += nb) {
    gather_gy<<<dim3(256 + 128, nb), 256, 0, stream>>>(idx, Mb, Wvb, G, Yt, b0);
    // A = tril(G * P^T): 136 tril tiles x nb, bn-desc LPT
    gemm_bt<1, false><<<dim3(nb * 136, 1, 1), 256, 0, stream>>>(
        G, T_DIM, (ll)T_DIM * T_DIM, P, T_DIM, 0,
        Abuf, T_DIM, (ll)T_DIM * T_DIM, T_DIM, 0.f);
    // out = A * Yt^T + 0.001, causal-K, bm-desc LPT
    gemm_bt<2, true><<<dim3((V_DIM / 128) * nb * NT, 1, 1), 256, 0, stream>>>(
        Abuf, T_DIM, (ll)T_DIM * T_DIM, Yt, T_DIM, (ll)V_DIM * T_DIM,
        out + (ll)b0 * T_DIM * V_DIM, V_DIM, (ll)T_DIM * V_DIM,
        T_DIM, 0.001f);
  }
}